// Round 11
// baseline (35.392 us; speedup 1.0000x reference)
//
#include <hip/hip_runtime.h>
#include <math.h>

#define TT 512
#define KP 4

typedef unsigned long long u64;

// Block-wide LDS barrier: waits DS ops only; global stores stay in flight.
#define SYNCL() asm volatile("s_waitcnt lgkmcnt(0)\n\ts_barrier" ::: "memory")
// In-wave DS fence.
#define SYNCW() do { asm volatile("s_waitcnt lgkmcnt(0)" ::: "memory"); \
                     __builtin_amdgcn_sched_barrier(0); } while (0)

// 512 blocks x 512 threads (8 waves). Block owns rows bn = blk*4 + r, r=0..3.
// Waves 0-1: compute team (wave h owns FFT half h; wave 0 does topk/params).
// Waves 2-7: store team (stores row r-1 while row r is computed).
__global__ __launch_bounds__(512, 4) void periodicity_kernel(const float* __restrict__ x,
                                                             float* __restrict__ out) {
    const int bid  = blockIdx.x;                    // 0..511
    const int blk  = (bid & 7) * 64 + (bid >> 3);   // XCD-grouped, bijective (512 = 8*64)
    const int tid  = threadIdx.x;
    const int lane = tid & 63;
    const int wid  = tid >> 6;                      // 0..7

    __shared__ float2 tw[TT];                       // tw[m] = e^{-2*pi*i*m/512}
    __shared__ __align__(16) float rowl[2][TT];     // double-buffered natural-order row
    __shared__ __align__(16) float2 buf[TT];        // FFT working buffer (half h = wave h)
    __shared__ __align__(16) u64 keys[256];         // (mag_bits<<32)|(256-f)
    __shared__ int pst[2][12];                      // per[4], cyc[4], st[4] (dbuf)

    const int b  = blk >> 4;                        // bn = b*64 + (n0 + r)
    const int n0 = (blk & 15) << 2;
    const size_t VOFF = (size_t)2048 * KP * 64 * 64;   // 33,554,432

    // ---- compute waves prefetch row 0 into registers ----
    float cur[8], nxt[8];
    const float* xb = x + (size_t)b * (TT * 64);
    if (wid < 2) {
        const float* xc = xb + n0;                  // row 0 = column n0
        #pragma unroll
        for (int q = 0; q < 8; ++q) cur[q] = xc[(size_t)(lane + 64 * q) * 64];
    }

    // ---- twiddle table: 512 threads, one sincosf each ----
    {
        float s, c;
        sincosf((float)(2.0 * M_PI / 512.0) * (float)tid, &s, &c);
        tw[tid] = make_float2(c, -s);
    }
    SYNCL();   // prologue barrier: tw ready

    for (int r = 0; r < 5; ++r) {
        const int slot = r & 1, pslot = slot ^ 1;

        // ================== phase A (before BAR1) ==================
        if (wid < 2 && r < 4) {
            const int h = wid;
            // prefetch next row (held in regs across the iteration)
            if (r < 3) {
                const float* xc = xb + (n0 + r + 1);
                #pragma unroll
                for (int q = 0; q < 8; ++q) nxt[q] = xc[(size_t)(lane + 64 * q) * 64];
            }
            // publish natural-order row for store team / refine
            if (h == 0) {
                #pragma unroll
                for (int q = 0; q < 4; ++q) rowl[slot][lane + 64 * q] = cur[q];
            } else {
                #pragma unroll
                for (int q = 0; q < 4; ++q) rowl[slot][256 + lane + 64 * q] = cur[4 + q];
            }
            // folded radix-2 first DIF stage (from registers)
            if (h == 0) {
                #pragma unroll
                for (int q = 0; q < 4; ++q)
                    buf[lane + 64 * q] = make_float2(cur[q] + cur[4 + q], 0.f);
            } else {
                #pragma unroll
                for (int q = 0; q < 4; ++q) {
                    const int j = lane + 64 * q;
                    float dif = cur[q] - cur[4 + q];
                    float2 t = tw[j];
                    buf[256 + j] = make_float2(dif * t.x, dif * t.y);
                }
            }
            SYNCW();

            // 3 radix-4 DIF stages on half h (in-wave fences only)
            float2* bb = &buf[h << 8];
            #pragma unroll
            for (int stg = 0; stg < 3; ++stg) {
                const int Q  = 64 >> (2 * stg);          // 64,16,4
                const int g  = lane >> (6 - 2 * stg);
                const int i  = lane & (Q - 1);
                const int base = g * (Q << 2) + i;
                float2 x0 = bb[base],         x1 = bb[base + Q];
                float2 x2 = bb[base + 2 * Q], x3 = bb[base + 3 * Q];
                float2 A  = make_float2(x0.x + x2.x, x0.y + x2.y);
                float2 Bm = make_float2(x0.x - x2.x, x0.y - x2.y);
                float2 Cc = make_float2(x1.x + x3.x, x1.y + x3.y);
                float2 D  = make_float2(x1.x - x3.x, x1.y - x3.y);
                float2 y0 = make_float2(A.x + Cc.x, A.y + Cc.y);
                float2 y2 = make_float2(A.x - Cc.x, A.y - Cc.y);
                float2 y1 = make_float2(Bm.x + D.y, Bm.y - D.x);   // Bm - i*D
                float2 y3 = make_float2(Bm.x - D.y, Bm.y + D.x);   // Bm + i*D
                const int m = i << (1 + 2 * stg);
                float2 t1 = tw[m], t2 = tw[2 * m], t3 = tw[3 * m];
                bb[base]         = y0;
                bb[base + Q]     = make_float2(y1.x * t1.x - y1.y * t1.y, y1.x * t1.y + y1.y * t1.x);
                bb[base + 2 * Q] = make_float2(y2.x * t2.x - y2.y * t2.y, y2.x * t2.y + y2.y * t2.x);
                bb[base + 3 * Q] = make_float2(y3.x * t3.x - y3.y * t3.y, y3.x * t3.y + y3.y * t3.x);
                SYNCW();
            }

            // stage 3 (Q=1, twiddles=1) fused with mag^2 + vectorized key write
            {
                const int g = lane;
                const int base = g << 2;
                float2 x0 = bb[base],     x1 = bb[base + 1];
                float2 x2 = bb[base + 2], x3 = bb[base + 3];
                float2 A  = make_float2(x0.x + x2.x, x0.y + x2.y);
                float2 Bm = make_float2(x0.x - x2.x, x0.y - x2.y);
                float2 Cc = make_float2(x1.x + x3.x, x1.y + x3.y);
                float2 D  = make_float2(x1.x - x3.x, x1.y - x3.y);
                float2 y0 = make_float2(A.x + Cc.x, A.y + Cc.y);
                float2 y2 = make_float2(A.x - Cc.x, A.y - Cc.y);
                float2 y1 = make_float2(Bm.x + D.y, Bm.y - D.x);
                float2 y3 = make_float2(Bm.x - D.y, Bm.y + D.x);
                const int revg = ((g & 3) << 4) | (((g >> 2) & 3) << 2) | ((g >> 4) & 3);
                const int f0 = 2 * revg + h;
                float m0 = y0.x * y0.x + y0.y * y0.y;
                float m1 = y1.x * y1.x + y1.y * y1.y;
                float m2 = y2.x * y2.x + y2.y * y2.y;
                u64 kA, kB;
                if (f0 == 0) {   // (h=0,g=0): keep f=128, f=256
                    kA = ((u64)__float_as_uint(m1) << 32) | (u64)(256 - 128);
                    kB = ((u64)__float_as_uint(m2) << 32) | (u64)(256 - 256);
                } else {         // keep f0, f0+128
                    kA = ((u64)__float_as_uint(m0) << 32) | (u64)(256 - f0);
                    kB = ((u64)__float_as_uint(m1) << 32) | (u64)(256 - (f0 + 128));
                }
                ((ulonglong2*)keys)[(h << 6) + g] = make_ulonglong2(kA, kB);
            }
        }

        // store team, segment A: row r-1, k = 0,1
        if (wid >= 2 && r >= 1) {
            const int bnp = b * 64 + n0 + (r - 1);
            float* outv = out + (size_t)bnp * (KP * 64 * 64);
            const int idx0 = (wid - 2) * 64 + lane;    // 0..383
            #pragma unroll
            for (int k2 = 0; k2 < 2; ++k2) {
                const int P = pst[pslot][k2], C = pst[pslot][4 + k2], S0 = pst[pslot][8 + k2];
                for (int i = idx0; i < 1024; i += 384) {
                    const int c  = i >> 4;
                    const int p0 = (i & 15) << 2;
                    float4 v = make_float4(0.f, 0.f, 0.f, 0.f);
                    if (c < C) {
                        const int base = S0 + c * P;
                        if (p0 + 3 < P) {
                            v.x = rowl[pslot][base + p0];
                            v.y = rowl[pslot][base + p0 + 1];
                            v.z = rowl[pslot][base + p0 + 2];
                            v.w = rowl[pslot][base + p0 + 3];
                        } else {
                            if (p0     < P) v.x = rowl[pslot][base + p0];
                            if (p0 + 1 < P) v.y = rowl[pslot][base + p0 + 1];
                            if (p0 + 2 < P) v.z = rowl[pslot][base + p0 + 2];
                            if (p0 + 3 < P) v.w = rowl[pslot][base + p0 + 3];
                        }
                    }
                    *(float4*)(outv + (size_t)k2 * 4096 + (size_t)i * 4) = v;
                }
            }
        }

        SYNCL();   // BAR1: keys + rowl[slot] ready

        // ================== phase B (after BAR1) ==================
        if (wid == 0 && r < 4) {
            // in-wave top-8 of 256 keys (value desc, bin asc)
            int   fbin[8];
            float cmag[8];
            {
                const ulonglong2* kv = (const ulonglong2*)keys;
                ulonglong2 p0v = kv[lane * 2];
                ulonglong2 p1v = kv[lane * 2 + 1];
                u64 k0 = p0v.x, k1 = p0v.y, k2 = p1v.x, k3 = p1v.y;
                #define CSWAP(a, b) { if (a < b) { u64 _t = a; a = b; b = _t; } }
                CSWAP(k0, k1) CSWAP(k2, k3) CSWAP(k0, k2) CSWAP(k1, k3) CSWAP(k1, k2)
                #undef CSWAP
                #pragma unroll
                for (int rr = 0; rr < 8; ++rr) {
                    u64 w = k0;
                    #pragma unroll
                    for (int off = 32; off >= 1; off >>= 1) {
                        u64 o = __shfl_xor(w, off);
                        if (o > w) w = o;
                    }
                    if (k0 == w) { k0 = k1; k1 = k2; k2 = k3; k3 = 0; }
                    fbin[rr] = 256 - (int)(w & 0xff);
                    cmag[rr] = __uint_as_float((unsigned)(w >> 32));
                }
            }

            // gap check (uniform across wave)
            const bool needRefine =
                ((cmag[0] - cmag[1]) <= 1e-4f * cmag[0]) || ((cmag[1] - cmag[2]) <= 1e-4f * cmag[1]) ||
                ((cmag[2] - cmag[3]) <= 1e-4f * cmag[2]) || ((cmag[3] - cmag[4]) <= 1e-4f * cmag[3]);

            int bins[KP];
            if (!needRefine) {
                #pragma unroll
                for (int k = 0; k < KP; ++k) bins[k] = fbin[k];
            } else {
                // f64 refine: 8 candidates x 8 lanes, 64 samples/lane (rare)
                const int cid = lane >> 3;
                const int sub = lane & 7;
                int fc;
                switch (cid) {
                    case 0: fc = fbin[0]; break;
                    case 1: fc = fbin[1]; break;
                    case 2: fc = fbin[2]; break;
                    case 3: fc = fbin[3]; break;
                    case 4: fc = fbin[4]; break;
                    case 5: fc = fbin[5]; break;
                    case 6: fc = fbin[6]; break;
                    default: fc = fbin[7]; break;
                }
                const int t0 = sub * 64;
                const double W = 6.2831853071795864769 / 512.0;
                double zr, zi, wr, wi;
                sincos(W * (double)((fc * t0) & 511), &zi, &zr);
                sincos(W * (double)fc, &wi, &wr);
                double ar = 0.0, ai = 0.0;
                const float4* r4 = (const float4*)rowl[slot];
                #pragma unroll
                for (int v4i = 0; v4i < 16; ++v4i) {
                    float4 xv = r4[sub * 16 + v4i];
                    #define STEP(comp)                                   \
                        { double xd = (double)xv.comp;                   \
                          ar = fma(xd, zr, ar); ai = fma(xd, zi, ai);    \
                          double tq = zr * wr - zi * wi;                 \
                          zi = fma(zr, wi, zi * wr); zr = tq; }
                    STEP(x) STEP(y) STEP(z) STEP(w)
                    #undef STEP
                }
                #pragma unroll
                for (int off = 4; off >= 1; off >>= 1) {
                    ar += __shfl_xor(ar, off);
                    ai += __shfl_xor(ai, off);
                }
                double Vg = ar * ar + ai * ai;   // every lane of group cid holds V[cid]
                double V[8];
                #pragma unroll
                for (int j = 0; j < 8; ++j) V[j] = __shfl(Vg, j * 8);
                unsigned chosen = 0;
                #pragma unroll
                for (int k = 0; k < KP; ++k) {
                    double bv = -1.0; int bbin = 0x7fffffff; int bj = 0;
                    #pragma unroll
                    for (int j = 0; j < 8; ++j) {
                        if (chosen & (1u << j)) continue;
                        if (V[j] > bv || (V[j] == bv && fbin[j] < bbin)) { bv = V[j]; bbin = fbin[j]; bj = j; }
                    }
                    chosen |= (1u << bj);
                    bins[k] = bbin;
                }
            }

            // params: publish pst[slot] + global params write
            const int bn = b * 64 + n0 + r;
            if (lane == 0) {
                #pragma unroll
                for (int k = 0; k < KP; ++k) {
                    int p = TT / bins[k];
                    p = p < 8 ? 8 : (p > 64 ? 64 : p);
                    const int cy = TT / p;
                    pst[slot][k]     = p;
                    pst[slot][4 + k] = cy;
                    pst[slot][8 + k] = TT - cy * p;
                    out[VOFF + (size_t)bn * KP + k]        = (float)p;
                    out[VOFF + 8192 + (size_t)bn * KP + k] = (float)cy;
                }
            }
        }

        // store team, segment B: row r-1, k = 2,3
        if (wid >= 2 && r >= 1) {
            const int bnp = b * 64 + n0 + (r - 1);
            float* outv = out + (size_t)bnp * (KP * 64 * 64);
            const int idx0 = (wid - 2) * 64 + lane;
            #pragma unroll
            for (int k2 = 2; k2 < 4; ++k2) {
                const int P = pst[pslot][k2], C = pst[pslot][4 + k2], S0 = pst[pslot][8 + k2];
                for (int i = idx0; i < 1024; i += 384) {
                    const int c  = i >> 4;
                    const int p0 = (i & 15) << 2;
                    float4 v = make_float4(0.f, 0.f, 0.f, 0.f);
                    if (c < C) {
                        const int base = S0 + c * P;
                        if (p0 + 3 < P) {
                            v.x = rowl[pslot][base + p0];
                            v.y = rowl[pslot][base + p0 + 1];
                            v.z = rowl[pslot][base + p0 + 2];
                            v.w = rowl[pslot][base + p0 + 3];
                        } else {
                            if (p0     < P) v.x = rowl[pslot][base + p0];
                            if (p0 + 1 < P) v.y = rowl[pslot][base + p0 + 1];
                            if (p0 + 2 < P) v.z = rowl[pslot][base + p0 + 2];
                            if (p0 + 3 < P) v.w = rowl[pslot][base + p0 + 3];
                        }
                    }
                    *(float4*)(outv + (size_t)k2 * 4096 + (size_t)i * 4) = v;
                }
            }
        }

        SYNCL();   // BAR2: pst[slot]/rowl[slot] ready for next iter's store team

        if (wid < 2 && r < 4) {
            #pragma unroll
            for (int q = 0; q < 8; ++q) cur[q] = nxt[q];
        }
    }
}

extern "C" void kernel_launch(void* const* d_in, const int* in_sizes, int n_in,
                              void* d_out, int out_size, void* d_ws, size_t ws_size,
                              hipStream_t stream) {
    const float* x = (const float*)d_in[0];
    float* out = (float*)d_out;
    hipLaunchKernelGGL(periodicity_kernel, dim3(512), dim3(512), 0, stream, x, out);
}